// Round 3
// baseline (171.993 us; speedup 1.0000x reference)
//
#include <hip/hip_runtime.h>

constexpr int F = 2048;            // NUM_FEATURES
constexpr int NROWS = 8192;        // rows
constexpr float EPS = 1e-6f;
constexpr int S4 = F / 4;          // 512 float4 per row

constexpr int NBLOCKS = 512;       // 8 colgroups x 64 rowgroups
constexpr int RPT = 32;            // rows per thread (kept in registers)
// block tile: 64 float4-cols x 128 rows; thread: lc = col, sg = 32-row subgroup

// ws layout: acc[2F] floats (sum, sumsq) then barrier counter.
// memsetAsync zeroes acc + counter each call (ws is poisoned 0xAA otherwise).

__global__ __launch_bounds__(256, 2) void fused_kernel(const float* __restrict__ x,
                                                       float* __restrict__ out,
                                                       float* __restrict__ acc,
                                                       unsigned* __restrict__ bar) {
    __shared__ float4 lS[3 * 64];
    __shared__ float4 lQ[3 * 64];
    __shared__ float  sr[256];     // rstd per scalar col of this colgroup
    __shared__ float  sb[256];     // -mean*rstd

    const int tid = threadIdx.x;
    const int lc  = tid & 63;
    const int sg  = tid >> 6;
    const int cg  = blockIdx.x & 7;      // colgroup
    const int rg  = blockIdx.x >> 3;     // rowgroup
    const int c4  = cg * 64 + lc;        // float4 column
    const int row0 = rg * 128 + sg * 32;

    const float4* __restrict__ xv = reinterpret_cast<const float4*>(x);
    float4* __restrict__ ov       = reinterpret_cast<float4*>(out);

    // ---- Phase 1: load tile into registers, accumulate sum/sumsq ----
    float4 v[RPT];
    float4 s = make_float4(0.f, 0.f, 0.f, 0.f);
    float4 q = make_float4(0.f, 0.f, 0.f, 0.f);
    const size_t base = (size_t)row0 * S4 + (size_t)c4;
#pragma unroll
    for (int r = 0; r < RPT; ++r) {
        v[r] = xv[base + (size_t)r * S4];
    }
#pragma unroll
    for (int r = 0; r < RPT; ++r) {
        s.x += v[r].x;  s.y += v[r].y;  s.z += v[r].z;  s.w += v[r].w;
        q.x += v[r].x * v[r].x;  q.y += v[r].y * v[r].y;
        q.z += v[r].z * v[r].z;  q.w += v[r].w * v[r].w;
    }

    // cross-subgroup reduce in LDS, then 64 threads do the atomics
    if (sg != 0) {
        lS[(sg - 1) * 64 + lc] = s;
        lQ[(sg - 1) * 64 + lc] = q;
    }
    __syncthreads();
    if (sg == 0) {
#pragma unroll
        for (int k = 0; k < 3; ++k) {
            float4 t = lS[k * 64 + lc];
            float4 u = lQ[k * 64 + lc];
            s.x += t.x;  s.y += t.y;  s.z += t.z;  s.w += t.w;
            q.x += u.x;  q.y += u.y;  q.z += u.z;  q.w += u.w;
        }
        float* __restrict__ sum   = acc;
        float* __restrict__ sumsq = acc + F;
        const int c = c4 * 4;
        atomicAdd(&sum[c + 0], s.x);
        atomicAdd(&sum[c + 1], s.y);
        atomicAdd(&sum[c + 2], s.z);
        atomicAdd(&sum[c + 3], s.w);
        atomicAdd(&sumsq[c + 0], q.x);
        atomicAdd(&sumsq[c + 1], q.y);
        atomicAdd(&sumsq[c + 2], q.z);
        atomicAdd(&sumsq[c + 3], q.w);
    }

    // ---- Grid barrier (all 512 blocks co-resident: 2 blocks/CU by launch_bounds) ----
    // __syncthreads() drains vmcnt(0) before s_barrier, so this block's atomics are
    // globally complete before we bump the counter.
    __syncthreads();
    if (tid == 0) {
        __threadfence();                       // release (agent scope)
        atomicAdd(bar, 1u);
        int guard = 0;
        while (atomicAdd(bar, 0u) < (unsigned)NBLOCKS) {
            __builtin_amdgcn_s_sleep(2);
            if (++guard > (1 << 27)) break;    // safety net: never triggers in practice
        }
        __threadfence();                       // acquire: invalidate stale L1/L2 lines
    }
    __syncthreads();

    // ---- Phase 2: finalize stats for this block's 256 scalar columns ----
    {
        const int col = cg * 256 + tid;
        const float s1 = acc[col];
        const float s2 = acc[col + F];
        const float mean = s1 * (1.0f / (float)NROWS);
        float var = (s2 - s1 * mean) * (1.0f / (float)(NROWS - 1));
        var = fmaxf(var, 0.0f);
        const float r = rsqrtf(var + EPS);
        sr[tid] = r;
        sb[tid] = -mean * r;
    }
    __syncthreads();

    // ---- Phase 3: normalize from registers, stream out ----
    const float4 r4 = reinterpret_cast<const float4*>(sr)[lc];
    const float4 b4 = reinterpret_cast<const float4*>(sb)[lc];
#pragma unroll
    for (int r = 0; r < RPT; ++r) {
        float4 o;
        o.x = fmaf(v[r].x, r4.x, b4.x);
        o.y = fmaf(v[r].y, r4.y, b4.y);
        o.z = fmaf(v[r].z, r4.z, b4.z);
        o.w = fmaf(v[r].w, r4.w, b4.w);
        ov[base + (size_t)r * S4] = o;
    }
}

extern "C" void kernel_launch(void* const* d_in, const int* in_sizes, int n_in,
                              void* d_out, int out_size, void* d_ws, size_t ws_size,
                              hipStream_t stream) {
    const float* x = (const float*)d_in[0];
    // running_mean / running_var are wiped by the Welford recurrence (n=1 / n=2).
    float* out    = (float*)d_out;
    float* acc    = (float*)d_ws;                       // 2F floats = 16 KB
    unsigned* bar = (unsigned*)((char*)d_ws + 2 * F * sizeof(float));

    // zero accumulators + barrier counter (ws is re-poisoned 0xAA before every call)
    hipMemsetAsync(d_ws, 0, 2 * F * sizeof(float) + 64, stream);

    fused_kernel<<<NBLOCKS, 256, 0, stream>>>(x, out, acc, bar);
}